// Round 7
// baseline (491.359 us; speedup 1.0000x reference)
//
#include <hip/hip_runtime.h>
#include <hip/hip_bf16.h>

#define NN 50000
#define EE 800000
#define DIN 1433
#define KTOT 1432
#define NKT1 45         // ceil(1432/32) k-tiles, full K
#define NB 196          // ceil(50000/256)
#define EPSC 1e-7f
#define MINN 1e-15f
#define MAXN 1e6f

typedef __attribute__((ext_vector_type(8))) short bf16x8;
typedef __attribute__((ext_vector_type(4))) float f32x4;

// ---- workspace layout (float offsets) ----
#define WF_OFF     0                          // 45*4096 ushorts = 92160 floats
#define XT_OFF     92160                      // 50000*64
#define XT3_OFF    (XT_OFF + 3200000)         // 50000*8
#define CNT_OFF    (XT3_OFF + 400000)         // 50000 ints
#define ROWPTR_OFF (CNT_OFF + 50000)          // 50002 ints (padded)
#define CUR_OFF    (ROWPTR_OFF + 50002)       // 50000 ints
#define BSUM_OFF   (CUR_OFF + 50000)          // 256 ints
#define BOFF_OFF   (BSUM_OFF + 256)           // 256 ints
#define EP_OFF     (BOFF_OFF + 256)           // 800000 uint2 (8B aligned)

__device__ __forceinline__ float wsum(float v) {
#pragma unroll
  for (int o = 1; o < 64; o <<= 1) v += __shfl_xor(v, o, 64);
  return v;
}

__device__ __forceinline__ float gsum8(float v) {
#pragma unroll
  for (int o = 1; o < 8; o <<= 1) v += __shfl_xor(v, o, 64);
  return v;
}

__device__ __forceinline__ void split_bf(float v, unsigned int& hbits16, unsigned int& lbits16) {
  unsigned int b = __float_as_uint(v);
  unsigned int hb = b & 0xFFFF0000u;
  float r = v - __uint_as_float(hb);
  unsigned int lb = __float_as_uint(r);
  lbits16 = (lb + 0x7FFFu + ((lb >> 16) & 1u)) >> 16;
  hbits16 = hb >> 16;
}

// ===================== node-chain math (validated R1-R6) =====================
__device__ float bias_tangent(const float* b, int lane, int D) {
  const bool sp = (lane >= 1) && (lane < D);
  float bsp = sp ? b[lane] : 0.f;
  float rb = fmaxf(sqrtf(wsum(bsp * bsp)), MINN);
  float bsh = sinhf(rb);
  float hb = sp ? bsh * bsp / rb : 0.f;
  float hbn2 = wsum(hb * hb);
  float hb0 = sqrtf(fmaxf(1.f + hbn2, EPSC));
  float hbyn = fmaxf(sqrtf(hbn2), MINN);
  return sp ? acoshf(fmaxf(hb0, 1.f + EPSC)) * hb / hbyn : 0.f;
}

__device__ float chain_with_u(float z, float u, int lane, int D) {
  const bool sp = (lane >= 1) && (lane < D);
  float s = sp ? z : 0.f;
  float r = fmaxf(sqrtf(wsum(s * s)), MINN);
  float sh = sinhf(r);
  float y = sp ? sh * s / r : 0.f;
  float yn2 = wsum(y * y);
  float x0 = sqrtf(fmaxf(1.f + yn2, EPSC));
  float y_norm = fmaxf(sqrtf(yn2), MINN);
  float ynv = sp ? y / y_norm : 0.f;
  float alpha = wsum(ynv * u);
  float wsp = sp ? u - alpha * (1.f - x0) * ynv : 0.f;
  float ux = wsum(y * wsp);
  float v0 = ux / fmaxf(x0, EPSC);
  float vt = (lane == 0) ? v0 : wsp;
  float md = wsum(vt * vt) - 2.f * v0 * v0;
  float nu = sqrtf(fmaxf(md, EPSC));
  nu = fminf(nu, MAXN);
  float th = fmaxf(nu, MINN);
  float cth = coshf(th), sth = sinhf(th);
  float resx = (lane == 0) ? x0 : y;
  float eres = cth * resx + sth * vt / th;
  float en2 = wsum(sp ? eres * eres : 0.f);
  float e0 = sqrtf(fmaxf(1.f + en2, EPSC));
  float eyn = fmaxf(sqrtf(en2), MINN);
  return sp ? acoshf(fmaxf(e0, 1.f + EPSC)) * eres / eyn : 0.f;
}

__device__ float agg_act_chain(float sin_, int lane, int D) {
  const bool sp = (lane >= 1) && (lane < D);
  float s = sp ? sin_ : 0.f;
  float r = fmaxf(sqrtf(wsum(s * s)), MINN);
  float sh = sinhf(r);
  float g = sp ? sh * s / r : 0.f;
  float gn2 = wsum(g * g);
  float g0 = sqrtf(fmaxf(1.f + gn2, EPSC));
  float gyn = fmaxf(sqrtf(gn2), MINN);
  float l = sp ? acoshf(fmaxf(g0, 1.f + EPSC)) * g / gyn : 0.f;
  float t = fmaxf(l, 0.f);
  float rt = fmaxf(sqrtf(wsum(t * t)), MINN);
  float sht = sinhf(rt);
  float h = sp ? sht * t / rt : 0.f;
  float hn2 = wsum(h * h);
  float h0 = sqrtf(fmaxf(1.f + hn2, EPSC));
  float hyn = fmaxf(sqrtf(hn2), MINN);
  return sp ? acoshf(fmaxf(h0, 1.f + EPSC)) * h / hyn : 0.f;
}

__device__ float agg_act_chain8(float sin_, int f) {
  const bool sp = (f >= 1) && (f < 7);
  float s = sp ? sin_ : 0.f;
  float r = fmaxf(sqrtf(gsum8(s * s)), MINN);
  float sh = sinhf(r);
  float g = sp ? sh * s / r : 0.f;
  float gn2 = gsum8(g * g);
  float g0 = sqrtf(fmaxf(1.f + gn2, EPSC));
  float gyn = fmaxf(sqrtf(gn2), MINN);
  float l = sp ? acoshf(fmaxf(g0, 1.f + EPSC)) * g / gyn : 0.f;
  float t = fmaxf(l, 0.f);
  float rt = fmaxf(sqrtf(gsum8(t * t)), MINN);
  float sht = sinhf(rt);
  float h = sp ? sht * t / rt : 0.f;
  float hn2 = gsum8(h * h);
  float h0 = sqrtf(fmaxf(1.f + hn2, EPSC));
  float hyn = fmaxf(sqrtf(hn2), MINN);
  return sp ? acoshf(fmaxf(h0, 1.f + EPSC)) * h / hyn : 0.f;
}

// ===================== W1 -> MFMA-fragment-ready bf16 hi/lo (full K) ==========
__global__ __launch_bounds__(256) void prep_wfrag(const float* __restrict__ W1,
                                                  unsigned short* __restrict__ wfrag) {
  int idx = blockIdx.x * 256 + threadIdx.x;
  if (idx >= NKT1 * 8 * 64) return;
  int lane = idx & 63;
  int c = (idx >> 6) & 7;
  int kt = idx >> 9;
  int type = c >> 2, nt = c & 3;
  int col = nt * 16 + (lane & 15);
  unsigned short vals[8];
#pragma unroll
  for (int i = 0; i < 8; ++i) {
    int lk = kt * 32 + (lane >> 4) * 8 + i;
    float wv = (lk < KTOT) ? W1[col * DIN + lk + 1] : 0.f;
    unsigned int h16, l16;
    split_bf(wv, h16, l16);
    vals[i] = (unsigned short)((type == 0) ? h16 : l16);
  }
  unsigned short* dst = wfrag + (((size_t)kt * 8 + c) * 64 + lane) * 8;
#pragma unroll
  for (int i = 0; i < 8; ++i) dst[i] = vals[i];
}

// ======== GEMM1: barrier-free K-loop, all fragments direct-to-register =======
// A: lane reads 8 consecutive k of its own row (MFMA A layout) from x, splits
//    to bf16 hi/lo in regs. B: wfrag is fragment-ready, 64x16B coalesced reads,
//    L2-resident (368 KB shared by all waves). No LDS staging, no K-loop
//    barriers -> no vmcnt(0) drains; compiler pipelines across unroll-3.
__global__ __launch_bounds__(256) void gemm_node1(const float* __restrict__ x,
                                                  const unsigned short* __restrict__ wfrag,
                                                  const float* __restrict__ b1,
                                                  float* __restrict__ xt) {
  __shared__ float zbuf[64][68];   // wave-private rows: no barriers needed
  const int tid = threadIdx.x;
  const int w = tid >> 6, lane = tid & 63;
  const int row0 = blockIdx.x * 64;
  const int arow = row0 + w * 16 + (lane & 15);
  const bool rok = (arow < NN);
  const float* __restrict__ xr = x + (size_t)arow * DIN + 1;
  const int koct = (lane >> 4) * 8;   // 0,8,16,24

  f32x4 acc[4];
#pragma unroll
  for (int nt = 0; nt < 4; ++nt) acc[nt] = (f32x4){0.f, 0.f, 0.f, 0.f};

#pragma unroll 3
  for (int kt = 0; kt < NKT1; ++kt) {
    const int k0 = kt * 32 + koct;
    // A fragment: 8 consecutive k of this lane's row
    float av[8];
#pragma unroll
    for (int j = 0; j < 8; ++j) {
      int lk = k0 + j;
      av[j] = (rok && lk < KTOT) ? xr[lk] : 0.f;
    }
    // B fragments: 8 x (64 lanes x 16B contiguous) from L2-hot wfrag
    const unsigned short* wfb = wfrag + (size_t)kt * 4096 + lane * 8;
    bf16x8 bh[4], bl[4];
#pragma unroll
    for (int c = 0; c < 4; ++c) bh[c] = *(const bf16x8*)(wfb + c * 512);
#pragma unroll
    for (int c = 0; c < 4; ++c) bl[c] = *(const bf16x8*)(wfb + (4 + c) * 512);
    // split A to bf16 hi/lo in registers
    unsigned int h[8], l[8];
#pragma unroll
    for (int j = 0; j < 8; ++j) split_bf(av[j], h[j], l[j]);
    bf16x8 ah, al;
#pragma unroll
    for (int j = 0; j < 8; ++j) { ah[j] = (short)h[j]; al[j] = (short)l[j]; }
#pragma unroll
    for (int nt = 0; nt < 4; ++nt) {
      acc[nt] = __builtin_amdgcn_mfma_f32_16x16x32_bf16(ah, bh[nt], acc[nt], 0, 0, 0);
      acc[nt] = __builtin_amdgcn_mfma_f32_16x16x32_bf16(ah, bl[nt], acc[nt], 0, 0, 0);
      acc[nt] = __builtin_amdgcn_mfma_f32_16x16x32_bf16(al, bh[nt], acc[nt], 0, 0, 0);
    }
  }
  // ---- transpose via LDS (wave-private rows) -> lane=feature ----
#pragma unroll
  for (int nt = 0; nt < 4; ++nt)
#pragma unroll
    for (int i = 0; i < 4; ++i) {
      int r = w * 16 + (lane >> 4) * 4 + i;
      zbuf[r][nt * 16 + (lane & 15)] = acc[nt][i];
    }
  // ---- fused layer-1 chain: wave w handles rows w*16..w*16+15 ----
  float u1 = bias_tangent(b1, lane, 64);
  for (int nr = 0; nr < 16; ++nr) {
    int r = w * 16 + nr;
    float z = zbuf[r][lane];
    float o = chain_with_u(z, u1, lane, 64);
    int g = row0 + r;
    if (g < NN) xt[(size_t)g * 64 + lane] = o;
  }
}

// ===================== CSR build =====================
__global__ __launch_bounds__(256) void k_zero(int* __restrict__ cnt) {
  int i = blockIdx.x * 256 + threadIdx.x;
  if (i < NN) cnt[i] = 0;
}

__global__ __launch_bounds__(256) void k_hist(const int* __restrict__ row, int* __restrict__ cnt) {
  int e = blockIdx.x * 256 + threadIdx.x;
  if (e < EE) atomicAdd(&cnt[row[e]], 1);
}

__global__ __launch_bounds__(256) void k_blocksum(const int* __restrict__ cnt,
                                                  int* __restrict__ bsum) {
  __shared__ int wpart[4];
  int i = blockIdx.x * 256 + threadIdx.x;
  int v = (i < NN) ? cnt[i] : 0;
  int s = v;
#pragma unroll
  for (int o = 1; o < 64; o <<= 1) s += __shfl_xor(s, o, 64);
  if ((threadIdx.x & 63) == 0) wpart[threadIdx.x >> 6] = s;
  __syncthreads();
  if (threadIdx.x == 0) bsum[blockIdx.x] = wpart[0] + wpart[1] + wpart[2] + wpart[3];
}

__global__ __launch_bounds__(256) void k_scanb(const int* __restrict__ bsum,
                                               int* __restrict__ boff) {
  __shared__ int s[256];
  int t = threadIdx.x;
  int v = (t < NB) ? bsum[t] : 0;
  s[t] = v;
  __syncthreads();
  for (int o = 1; o < 256; o <<= 1) {
    int a = (t >= o) ? s[t - o] : 0;
    __syncthreads();
    s[t] += a;
    __syncthreads();
  }
  if (t < NB) boff[t] = s[t] - v;
}

__global__ __launch_bounds__(256) void k_apply(const int* __restrict__ cnt,
                                               const int* __restrict__ boff,
                                               int* __restrict__ rowptr, int* __restrict__ cur) {
  __shared__ int s[256];
  int i = blockIdx.x * 256 + threadIdx.x;
  int t = threadIdx.x;
  int v = (i < NN) ? cnt[i] : 0;
  s[t] = v;
  __syncthreads();
  for (int o = 1; o < 256; o <<= 1) {
    int a = (t >= o) ? s[t - o] : 0;
    __syncthreads();
    s[t] += a;
    __syncthreads();
  }
  int ex = s[t] - v + boff[blockIdx.x];
  if (i < NN) { rowptr[i] = ex; cur[i] = ex; }
  if (i == NN - 1) rowptr[NN] = EE;
}

__global__ __launch_bounds__(256) void k_scatter(const int* __restrict__ row,
                                                 const int* __restrict__ col,
                                                 const float* __restrict__ ew,
                                                 int* __restrict__ cur, uint2* __restrict__ ep) {
  int e = blockIdx.x * 256 + threadIdx.x;
  if (e < EE) {
    int p = atomicAdd(&cur[row[e]], 1);
    uint2 q;
    q.x = (unsigned int)col[e];
    q.y = __float_as_uint(ew[e]);
    ep[p] = q;
  }
}

// ===================== agg1 (gather, unroll-8) + chains + W2 ====
__global__ __launch_bounds__(256) void agg1_node2(const int* __restrict__ rowptr,
                                                  const uint2* __restrict__ ep,
                                                  const float* __restrict__ xt,
                                                  const float* __restrict__ W2,
                                                  const float* __restrict__ b2,
                                                  float* __restrict__ xt3) {
  const int node = blockIdx.x * 4 + (threadIdx.x >> 6);
  const int lane = threadIdx.x & 63;
  const int s0 = rowptr[node], s1 = rowptr[node + 1];
  float a0 = 0.f, a1 = 0.f, a2 = 0.f, a3 = 0.f;
  float a4 = 0.f, a5 = 0.f, a6 = 0.f, a7 = 0.f;
  int p = s0;
  for (; p + 8 <= s1; p += 8) {
    uint2 q0 = ep[p], q1 = ep[p + 1], q2 = ep[p + 2], q3 = ep[p + 3];
    uint2 q4 = ep[p + 4], q5 = ep[p + 5], q6 = ep[p + 6], q7 = ep[p + 7];
    a0 = fmaf(__uint_as_float(q0.y), xt[(size_t)q0.x * 64 + lane], a0);
    a1 = fmaf(__uint_as_float(q1.y), xt[(size_t)q1.x * 64 + lane], a1);
    a2 = fmaf(__uint_as_float(q2.y), xt[(size_t)q2.x * 64 + lane], a2);
    a3 = fmaf(__uint_as_float(q3.y), xt[(size_t)q3.x * 64 + lane], a3);
    a4 = fmaf(__uint_as_float(q4.y), xt[(size_t)q4.x * 64 + lane], a4);
    a5 = fmaf(__uint_as_float(q5.y), xt[(size_t)q5.x * 64 + lane], a5);
    a6 = fmaf(__uint_as_float(q6.y), xt[(size_t)q6.x * 64 + lane], a6);
    a7 = fmaf(__uint_as_float(q7.y), xt[(size_t)q7.x * 64 + lane], a7);
  }
  for (; p < s1; ++p) {
    uint2 q = ep[p];
    a0 = fmaf(__uint_as_float(q.y), xt[(size_t)q.x * 64 + lane], a0);
  }
  float acc = ((a0 + a1) + (a2 + a3)) + ((a4 + a5) + (a6 + a7));
  float xt2 = agg_act_chain(acc, lane, 64);
  float z2 = 0.f;
#pragma unroll
  for (int jj = 1; jj < 7; ++jj) {
    float wv = W2[jj * 64 + lane];
    float sjj = wsum(xt2 * wv);
    if (lane == jj) z2 = sjj;
  }
  float u2 = bias_tangent(b2, lane, 7);
  float o = chain_with_u(z2, u2, lane, 7);
  if (lane < 8) xt3[node * 8 + lane] = o;
}

// ===================== agg2 + final chain: 8 nodes per wave =====================
__global__ __launch_bounds__(256) void agg2_final(const int* __restrict__ rowptr,
                                                  const uint2* __restrict__ ep,
                                                  const float* __restrict__ xt3,
                                                  float* __restrict__ out) {
  const int node = blockIdx.x * 32 + (threadIdx.x >> 3);
  const int f = threadIdx.x & 7;
  const int nc = (node < NN) ? node : (NN - 1);
  const int s0 = rowptr[nc], s1 = rowptr[nc + 1];
  float a0 = 0.f, a1 = 0.f, a2 = 0.f, a3 = 0.f;
  int p = s0;
  for (; p + 4 <= s1; p += 4) {
    uint2 q0 = ep[p], q1 = ep[p + 1], q2 = ep[p + 2], q3 = ep[p + 3];
    a0 = fmaf(__uint_as_float(q0.y), xt3[(size_t)q0.x * 8 + f], a0);
    a1 = fmaf(__uint_as_float(q1.y), xt3[(size_t)q1.x * 8 + f], a1);
    a2 = fmaf(__uint_as_float(q2.y), xt3[(size_t)q2.x * 8 + f], a2);
    a3 = fmaf(__uint_as_float(q3.y), xt3[(size_t)q3.x * 8 + f], a3);
  }
  for (; p < s1; ++p) {
    uint2 q = ep[p];
    a0 = fmaf(__uint_as_float(q.y), xt3[(size_t)q.x * 8 + f], a0);
  }
  float acc = (a0 + a1) + (a2 + a3);
  float o = agg_act_chain8(acc, f);
  if (node < NN && f < 7) out[node * 7 + f] = o;
}

extern "C" void kernel_launch(void* const* d_in, const int* in_sizes, int n_in,
                              void* d_out, int out_size, void* d_ws, size_t ws_size,
                              hipStream_t stream) {
  const float* x = (const float*)d_in[0];
  const int* row = (const int*)d_in[1];
  const int* col = (const int*)d_in[2];
  const float* ew = (const float*)d_in[3];
  const float* W1 = (const float*)d_in[4];
  const float* b1 = (const float*)d_in[5];
  const float* W2 = (const float*)d_in[6];
  const float* b2 = (const float*)d_in[7];
  float* ws = (float*)d_ws;
  unsigned short* wfrag = (unsigned short*)(ws + WF_OFF);
  float* xt = ws + XT_OFF;
  float* xt3 = ws + XT3_OFF;
  int* cnt = (int*)(ws + CNT_OFF);
  int* rowptr = (int*)(ws + ROWPTR_OFF);
  int* cur = (int*)(ws + CUR_OFF);
  int* bsum = (int*)(ws + BSUM_OFF);
  int* boff = (int*)(ws + BOFF_OFF);
  uint2* ep = (uint2*)(ws + EP_OFF);
  float* out = (float*)d_out;

  // CSR build (two-level parallel scan)
  k_zero<<<dim3(NB), dim3(256), 0, stream>>>(cnt);
  k_hist<<<dim3(3125), dim3(256), 0, stream>>>(row, cnt);
  k_blocksum<<<dim3(NB), dim3(256), 0, stream>>>(cnt, bsum);
  k_scanb<<<dim3(1), dim3(256), 0, stream>>>(bsum, boff);
  k_apply<<<dim3(NB), dim3(256), 0, stream>>>(cnt, boff, rowptr, cur);
  k_scatter<<<dim3(3125), dim3(256), 0, stream>>>(row, col, ew, cur, ep);

  // layer 1: GEMM (barrier-free, direct-to-register fragments) + fused chain
  prep_wfrag<<<dim3(90), dim3(256), 0, stream>>>(W1, wfrag);
  gemm_node1<<<dim3(782), dim3(256), 0, stream>>>(x, wfrag, b1, xt);

  agg1_node2<<<dim3(12500), dim3(256), 0, stream>>>(rowptr, ep, xt, W2, b2, xt3);
  agg2_final<<<dim3(1563), dim3(256), 0, stream>>>(rowptr, ep, xt3, out);
}

// Round 8
// 377.291 us; speedup vs baseline: 1.3023x; 1.3023x over previous
//
#include <hip/hip_runtime.h>
#include <hip/hip_bf16.h>

#define NN 50000
#define EE 800000
#define DIN 1433
#define KTOT 1432
#define KHALF 716
#define NKT 23          // ceil(716/32) k-tiles per half
#define NB 196          // ceil(50000/256)
#define EPSC 1e-7f
#define MINN 1e-15f
#define MAXN 1e6f

typedef __attribute__((ext_vector_type(8))) short bf16x8;
typedef __attribute__((ext_vector_type(4))) float f32x4;

// ---- workspace layout (float offsets) ----
#define WF_OFF     0                          // 2*23*4096 ushorts = 94208 floats
#define Z1A_OFF    94208                      // 50000*64 (xt written in-place)
#define Z1B_OFF    (Z1A_OFF + 3200000)        // 50000*64
#define XT3_OFF    (Z1B_OFF + 3200000)        // 50000*8
#define CNT_OFF    (XT3_OFF + 400000)
#define ROWPTR_OFF (CNT_OFF + 50000)          // 50002 (padded)
#define CUR_OFF    (ROWPTR_OFF + 50002)
#define BSUM_OFF   (CUR_OFF + 50000)          // 256
#define BOFF_OFF   (BSUM_OFF + 256)           // 256
#define EP_OFF     (BOFF_OFF + 256)           // 800000 uint2 (even offset -> 8B aligned)
// end = 8,644,722 floats ≈ 34.6 MB (R2-proven size)

__device__ __forceinline__ float wsum(float v) {
#pragma unroll
  for (int o = 1; o < 64; o <<= 1) v += __shfl_xor(v, o, 64);
  return v;
}

__device__ __forceinline__ float gsum8(float v) {
#pragma unroll
  for (int o = 1; o < 8; o <<= 1) v += __shfl_xor(v, o, 64);
  return v;
}

__device__ __forceinline__ void split_bf(float v, unsigned int& hbits16, unsigned int& lbits16) {
  unsigned int b = __float_as_uint(v);
  unsigned int hb = b & 0xFFFF0000u;
  float r = v - __uint_as_float(hb);
  unsigned int lb = __float_as_uint(r);
  lbits16 = (lb + 0x7FFFu + ((lb >> 16) & 1u)) >> 16;
  hbits16 = hb >> 16;
}

// ---- fast transcendentals (v_exp_f32 / v_log_f32 / v_rcp) ----
// abs err <= ~1e-6 in live range; tolerance is 1.75e-3 with 2.4e-4 current margin.
__device__ __forceinline__ float fsinh(float x) {
  float e = __expf(x);
  return 0.5f * (e - __fdividef(1.f, e));
}
__device__ __forceinline__ float facoshp(float z) {   // z >= 1+EPSC (pre-clamped)
  return __logf(z + sqrtf(fmaxf(z * z - 1.f, 0.f)));
}

// ===================== node-chain math (fast-math variants) =====================
__device__ float bias_tangent(const float* b, int lane, int D) {
  const bool sp = (lane >= 1) && (lane < D);
  float bsp = sp ? b[lane] : 0.f;
  float rb = fmaxf(sqrtf(wsum(bsp * bsp)), MINN);
  float bsh = fsinh(rb);
  float hb = sp ? bsh * __fdividef(bsp, rb) : 0.f;
  float hbn2 = wsum(hb * hb);
  float hb0 = sqrtf(fmaxf(1.f + hbn2, EPSC));
  float hbyn = fmaxf(sqrtf(hbn2), MINN);
  return sp ? facoshp(fmaxf(hb0, 1.f + EPSC)) * __fdividef(hb, hbyn) : 0.f;
}

__device__ float chain_with_u(float z, float u, int lane, int D) {
  const bool sp = (lane >= 1) && (lane < D);
  float s = sp ? z : 0.f;
  float r = fmaxf(sqrtf(wsum(s * s)), MINN);
  float sh = fsinh(r);
  float y = sp ? sh * __fdividef(s, r) : 0.f;
  float yn2 = wsum(y * y);
  float x0 = sqrtf(fmaxf(1.f + yn2, EPSC));
  float y_norm = fmaxf(sqrtf(yn2), MINN);
  float ynv = sp ? __fdividef(y, y_norm) : 0.f;
  float alpha = wsum(ynv * u);
  float wsp = sp ? u - alpha * (1.f - x0) * ynv : 0.f;
  float ux = wsum(y * wsp);
  float v0 = __fdividef(ux, fmaxf(x0, EPSC));
  float vt = (lane == 0) ? v0 : wsp;
  float md = wsum(vt * vt) - 2.f * v0 * v0;
  float nu = sqrtf(fmaxf(md, EPSC));
  nu = fminf(nu, MAXN);
  float th = fmaxf(nu, MINN);
  float e = __expf(th), ei = __fdividef(1.f, e);
  float cth = 0.5f * (e + ei), sth = 0.5f * (e - ei);
  float resx = (lane == 0) ? x0 : y;
  float eres = fmaf(cth, resx, sth * __fdividef(vt, th));
  float en2 = wsum(sp ? eres * eres : 0.f);
  float e0 = sqrtf(fmaxf(1.f + en2, EPSC));
  float eyn = fmaxf(sqrtf(en2), MINN);
  return sp ? facoshp(fmaxf(e0, 1.f + EPSC)) * __fdividef(eres, eyn) : 0.f;
}

__device__ float agg_act_chain(float sin_, int lane, int D) {
  const bool sp = (lane >= 1) && (lane < D);
  float s = sp ? sin_ : 0.f;
  float r = fmaxf(sqrtf(wsum(s * s)), MINN);
  float sh = fsinh(r);
  float g = sp ? sh * __fdividef(s, r) : 0.f;
  float gn2 = wsum(g * g);
  float g0 = sqrtf(fmaxf(1.f + gn2, EPSC));
  float gyn = fmaxf(sqrtf(gn2), MINN);
  float l = sp ? facoshp(fmaxf(g0, 1.f + EPSC)) * __fdividef(g, gyn) : 0.f;
  float t = fmaxf(l, 0.f);
  float rt = fmaxf(sqrtf(wsum(t * t)), MINN);
  float sht = fsinh(rt);
  float h = sp ? sht * __fdividef(t, rt) : 0.f;
  float hn2 = wsum(h * h);
  float h0 = sqrtf(fmaxf(1.f + hn2, EPSC));
  float hyn = fmaxf(sqrtf(hn2), MINN);
  return sp ? facoshp(fmaxf(h0, 1.f + EPSC)) * __fdividef(h, hyn) : 0.f;
}

__device__ float agg_act_chain8(float sin_, int f) {
  const bool sp = (f >= 1) && (f < 7);
  float s = sp ? sin_ : 0.f;
  float r = fmaxf(sqrtf(gsum8(s * s)), MINN);
  float sh = fsinh(r);
  float g = sp ? sh * __fdividef(s, r) : 0.f;
  float gn2 = gsum8(g * g);
  float g0 = sqrtf(fmaxf(1.f + gn2, EPSC));
  float gyn = fmaxf(sqrtf(gn2), MINN);
  float l = sp ? facoshp(fmaxf(g0, 1.f + EPSC)) * __fdividef(g, gyn) : 0.f;
  float t = fmaxf(l, 0.f);
  float rt = fmaxf(sqrtf(gsum8(t * t)), MINN);
  float sht = fsinh(rt);
  float h = sp ? sht * __fdividef(t, rt) : 0.f;
  float hn2 = gsum8(h * h);
  float h0 = sqrtf(fmaxf(1.f + hn2, EPSC));
  float hyn = fmaxf(sqrtf(hn2), MINN);
  return sp ? facoshp(fmaxf(h0, 1.f + EPSC)) * __fdividef(h, hyn) : 0.f;
}

// ===================== W1 -> MFMA-fragment-ready bf16 hi/lo (2 halves) ========
__global__ __launch_bounds__(256) void prep_wfrag(const float* __restrict__ W1,
                                                  unsigned short* __restrict__ wfrag) {
  int idx = blockIdx.x * 256 + threadIdx.x;
  if (idx >= 2 * NKT * 8 * 64) return;
  int lane = idx & 63;
  int c = (idx >> 6) & 7;
  int rest = idx >> 9;
  int kt = rest % NKT;
  int half = rest / NKT;
  int type = c >> 2, nt = c & 3;
  int col = nt * 16 + (lane & 15);
  unsigned short vals[8];
#pragma unroll
  for (int i = 0; i < 8; ++i) {
    int lk = kt * 32 + (lane >> 4) * 8 + i;
    float wv = (lk < KHALF) ? W1[col * DIN + half * KHALF + lk + 1] : 0.f;
    unsigned int h16, l16;
    split_bf(wv, h16, l16);
    vals[i] = (unsigned short)((type == 0) ? h16 : l16);
  }
  unsigned short* dst = wfrag + (((size_t)(half * NKT + kt) * 8 + c) * 64 + lane) * 8;
#pragma unroll
  for (int i = 0; i < 8; ++i) dst[i] = vals[i];
}

// ======== GEMM1 half (BM=64, split-K=2, LDS-staged, reg-prefetch A) ==========
// grid (782, 2) -> 6256 waves = ~24/CU: 2x the occupancy of the fused full-K.
__global__ __launch_bounds__(256) void gemm_half(const float* __restrict__ x,
                                                 const unsigned short* __restrict__ wfrag,
                                                 float* __restrict__ z) {
  __shared__ __align__(16) unsigned short Ah[64][40];
  __shared__ __align__(16) unsigned short Al[64][40];
  __shared__ __align__(16) unsigned short Bf[8][64][8];
  const int tid = threadIdx.x;
  const int w = tid >> 6, lane = tid & 63;
  const int row0 = blockIdx.x * 64;
  const int half = blockIdx.y;
  const unsigned short* wf = wfrag + (size_t)half * NKT * 4096;
  float* zp = z + (size_t)half * 3200000;

  f32x4 acc[4];
#pragma unroll
  for (int nt = 0; nt < 4; ++nt) acc[nt] = (f32x4){0.f, 0.f, 0.f, 0.f};

  const int lrow = tid >> 2;        // 0..63
  const int kq = (tid & 3) * 8;     // 0,8,16,24
  const int gr = row0 + lrow;
  const bool rok = (gr < NN);
  const float* __restrict__ xr = x + (size_t)gr * DIN + 1 + half * KHALF;

  float v[8];
#pragma unroll
  for (int j = 0; j < 8; ++j) v[j] = rok ? xr[kq + j] : 0.f;   // kt=0 (kq+j<32<716)

  for (int kt = 0; kt < NKT; ++kt) {
    __syncthreads();
    {
      unsigned int h[8], l[8];
#pragma unroll
      for (int j = 0; j < 8; ++j) split_bf(v[j], h[j], l[j]);
      uint4 hw, lw;
      hw.x = h[0] | (h[1] << 16); hw.y = h[2] | (h[3] << 16);
      hw.z = h[4] | (h[5] << 16); hw.w = h[6] | (h[7] << 16);
      lw.x = l[0] | (l[1] << 16); lw.y = l[2] | (l[3] << 16);
      lw.z = l[4] | (l[5] << 16); lw.w = l[6] | (l[7] << 16);
      *(uint4*)&Ah[lrow][kq] = hw;
      *(uint4*)&Al[lrow][kq] = lw;
    }
    if (w == 0) {
      const unsigned short* src = wf + (size_t)kt * 4096 + lane * 8;
#pragma unroll
      for (int c = 0; c < 8; ++c) {
        __builtin_amdgcn_global_load_lds(
            (const __attribute__((address_space(1))) unsigned int*)(src + c * 512),
            (__attribute__((address_space(3))) unsigned int*)(&Bf[c][0][0]),
            16, 0, 0);
      }
    }
    __syncthreads();
    if (kt + 1 < NKT) {     // prefetch next tile's A into regs during MFMA phase
      const int k0n = (kt + 1) * 32;
#pragma unroll
      for (int j = 0; j < 8; ++j) {
        int lk = k0n + kq + j;
        v[j] = (rok && lk < KHALF) ? xr[lk] : 0.f;
      }
    }
    const int arow = w * 16 + (lane & 15);
    const int kb = (lane >> 4) * 8;
    bf16x8 ah = *(const bf16x8*)&Ah[arow][kb];
    bf16x8 al = *(const bf16x8*)&Al[arow][kb];
    bf16x8 bh[4], bl[4];
#pragma unroll
    for (int nt = 0; nt < 4; ++nt) {
      bh[nt] = *(const bf16x8*)&Bf[nt][lane][0];
      bl[nt] = *(const bf16x8*)&Bf[4 + nt][lane][0];
    }
#pragma unroll
    for (int nt = 0; nt < 4; ++nt) {
      acc[nt] = __builtin_amdgcn_mfma_f32_16x16x32_bf16(ah, bh[nt], acc[nt], 0, 0, 0);
      acc[nt] = __builtin_amdgcn_mfma_f32_16x16x32_bf16(ah, bl[nt], acc[nt], 0, 0, 0);
      acc[nt] = __builtin_amdgcn_mfma_f32_16x16x32_bf16(al, bh[nt], acc[nt], 0, 0, 0);
    }
  }
  // epilogue: D row=(lane>>4)*4+i, col=lane&15
#pragma unroll
  for (int nt = 0; nt < 4; ++nt)
#pragma unroll
    for (int i = 0; i < 4; ++i) {
      int g = row0 + w * 16 + (lane >> 4) * 4 + i;
      if (g < NN) zp[(size_t)g * 64 + nt * 16 + (lane & 15)] = acc[nt][i];
    }
}

// ===================== layer-1 node chain (z = z1a+z1b, writes in-place) ======
__global__ __launch_bounds__(256) void node1(const float* __restrict__ z1a,
                                             const float* __restrict__ z1b,
                                             const float* __restrict__ b1, float* xt) {
  const int node = blockIdx.x * 4 + (threadIdx.x >> 6);
  const int lane = threadIdx.x & 63;
  const int idx = node * 64 + lane;
  float z = z1a[idx] + z1b[idx];
  float u1 = bias_tangent(b1, lane, 64);
  float o = chain_with_u(z, u1, lane, 64);
  xt[idx] = o;
}

// ===================== CSR build =====================
__global__ __launch_bounds__(256) void k_zero(int* __restrict__ cnt) {
  int i = blockIdx.x * 256 + threadIdx.x;
  if (i < NN) cnt[i] = 0;
}

__global__ __launch_bounds__(256) void k_hist(const int* __restrict__ row, int* __restrict__ cnt) {
  int e = blockIdx.x * 256 + threadIdx.x;
  if (e < EE) atomicAdd(&cnt[row[e]], 1);
}

__global__ __launch_bounds__(256) void k_blocksum(const int* __restrict__ cnt,
                                                  int* __restrict__ bsum) {
  __shared__ int wpart[4];
  int i = blockIdx.x * 256 + threadIdx.x;
  int v = (i < NN) ? cnt[i] : 0;
  int s = v;
#pragma unroll
  for (int o = 1; o < 64; o <<= 1) s += __shfl_xor(s, o, 64);
  if ((threadIdx.x & 63) == 0) wpart[threadIdx.x >> 6] = s;
  __syncthreads();
  if (threadIdx.x == 0) bsum[blockIdx.x] = wpart[0] + wpart[1] + wpart[2] + wpart[3];
}

__global__ __launch_bounds__(256) void k_scanb(const int* __restrict__ bsum,
                                               int* __restrict__ boff) {
  __shared__ int s[256];
  int t = threadIdx.x;
  int v = (t < NB) ? bsum[t] : 0;
  s[t] = v;
  __syncthreads();
  for (int o = 1; o < 256; o <<= 1) {
    int a = (t >= o) ? s[t - o] : 0;
    __syncthreads();
    s[t] += a;
    __syncthreads();
  }
  if (t < NB) boff[t] = s[t] - v;
}

__global__ __launch_bounds__(256) void k_apply(const int* __restrict__ cnt,
                                               const int* __restrict__ boff,
                                               int* __restrict__ rowptr, int* __restrict__ cur) {
  __shared__ int s[256];
  int i = blockIdx.x * 256 + threadIdx.x;
  int t = threadIdx.x;
  int v = (i < NN) ? cnt[i] : 0;
  s[t] = v;
  __syncthreads();
  for (int o = 1; o < 256; o <<= 1) {
    int a = (t >= o) ? s[t - o] : 0;
    __syncthreads();
    s[t] += a;
    __syncthreads();
  }
  int ex = s[t] - v + boff[blockIdx.x];
  if (i < NN) { rowptr[i] = ex; cur[i] = ex; }
  if (i == NN - 1) rowptr[NN] = EE;
}

__global__ __launch_bounds__(256) void k_scatter(const int* __restrict__ row,
                                                 const int* __restrict__ col,
                                                 const float* __restrict__ ew,
                                                 int* __restrict__ cur, uint2* __restrict__ ep) {
  int e = blockIdx.x * 256 + threadIdx.x;
  if (e < EE) {
    int p = atomicAdd(&cur[row[e]], 1);
    uint2 q;
    q.x = (unsigned int)col[e];
    q.y = __float_as_uint(ew[e]);
    ep[p] = q;
  }
}

// ===================== agg1 (gather, unroll-8) + chains + W2 ====
__global__ __launch_bounds__(256) void agg1_node2(const int* __restrict__ rowptr,
                                                  const uint2* __restrict__ ep,
                                                  const float* __restrict__ xt,
                                                  const float* __restrict__ W2,
                                                  const float* __restrict__ b2,
                                                  float* __restrict__ xt3) {
  const int node = blockIdx.x * 4 + (threadIdx.x >> 6);
  const int lane = threadIdx.x & 63;
  const int s0 = rowptr[node], s1 = rowptr[node + 1];
  float a0 = 0.f, a1 = 0.f, a2 = 0.f, a3 = 0.f;
  float a4 = 0.f, a5 = 0.f, a6 = 0.f, a7 = 0.f;
  int p = s0;
  for (; p + 8 <= s1; p += 8) {
    uint2 q0 = ep[p], q1 = ep[p + 1], q2 = ep[p + 2], q3 = ep[p + 3];
    uint2 q4 = ep[p + 4], q5 = ep[p + 5], q6 = ep[p + 6], q7 = ep[p + 7];
    a0 = fmaf(__uint_as_float(q0.y), xt[(size_t)q0.x * 64 + lane], a0);
    a1 = fmaf(__uint_as_float(q1.y), xt[(size_t)q1.x * 64 + lane], a1);
    a2 = fmaf(__uint_as_float(q2.y), xt[(size_t)q2.x * 64 + lane], a2);
    a3 = fmaf(__uint_as_float(q3.y), xt[(size_t)q3.x * 64 + lane], a3);
    a4 = fmaf(__uint_as_float(q4.y), xt[(size_t)q4.x * 64 + lane], a4);
    a5 = fmaf(__uint_as_float(q5.y), xt[(size_t)q5.x * 64 + lane], a5);
    a6 = fmaf(__uint_as_float(q6.y), xt[(size_t)q6.x * 64 + lane], a6);
    a7 = fmaf(__uint_as_float(q7.y), xt[(size_t)q7.x * 64 + lane], a7);
  }
  for (; p < s1; ++p) {
    uint2 q = ep[p];
    a0 = fmaf(__uint_as_float(q.y), xt[(size_t)q.x * 64 + lane], a0);
  }
  float acc = ((a0 + a1) + (a2 + a3)) + ((a4 + a5) + (a6 + a7));
  float xt2 = agg_act_chain(acc, lane, 64);
  float z2 = 0.f;
#pragma unroll
  for (int jj = 1; jj < 7; ++jj) {
    float wv = W2[jj * 64 + lane];
    float sjj = wsum(xt2 * wv);
    if (lane == jj) z2 = sjj;
  }
  float u2 = bias_tangent(b2, lane, 7);
  float o = chain_with_u(z2, u2, lane, 7);
  if (lane < 8) xt3[node * 8 + lane] = o;
}

// ===================== agg2 + final chain: 8 nodes per wave =====================
__global__ __launch_bounds__(256) void agg2_final(const int* __restrict__ rowptr,
                                                  const uint2* __restrict__ ep,
                                                  const float* __restrict__ xt3,
                                                  float* __restrict__ out) {
  const int node = blockIdx.x * 32 + (threadIdx.x >> 3);
  const int f = threadIdx.x & 7;
  const int nc = (node < NN) ? node : (NN - 1);
  const int s0 = rowptr[nc], s1 = rowptr[nc + 1];
  float a0 = 0.f, a1 = 0.f, a2 = 0.f, a3 = 0.f;
  int p = s0;
  for (; p + 4 <= s1; p += 4) {
    uint2 q0 = ep[p], q1 = ep[p + 1], q2 = ep[p + 2], q3 = ep[p + 3];
    a0 = fmaf(__uint_as_float(q0.y), xt3[(size_t)q0.x * 8 + f], a0);
    a1 = fmaf(__uint_as_float(q1.y), xt3[(size_t)q1.x * 8 + f], a1);
    a2 = fmaf(__uint_as_float(q2.y), xt3[(size_t)q2.x * 8 + f], a2);
    a3 = fmaf(__uint_as_float(q3.y), xt3[(size_t)q3.x * 8 + f], a3);
  }
  for (; p < s1; ++p) {
    uint2 q = ep[p];
    a0 = fmaf(__uint_as_float(q.y), xt3[(size_t)q.x * 8 + f], a0);
  }
  float acc = (a0 + a1) + (a2 + a3);
  float o = agg_act_chain8(acc, f);
  if (node < NN && f < 7) out[node * 7 + f] = o;
}

extern "C" void kernel_launch(void* const* d_in, const int* in_sizes, int n_in,
                              void* d_out, int out_size, void* d_ws, size_t ws_size,
                              hipStream_t stream) {
  const float* x = (const float*)d_in[0];
  const int* row = (const int*)d_in[1];
  const int* col = (const int*)d_in[2];
  const float* ew = (const float*)d_in[3];
  const float* W1 = (const float*)d_in[4];
  const float* b1 = (const float*)d_in[5];
  const float* W2 = (const float*)d_in[6];
  const float* b2 = (const float*)d_in[7];
  float* ws = (float*)d_ws;
  unsigned short* wfrag = (unsigned short*)(ws + WF_OFF);
  float* z1a = ws + Z1A_OFF;
  float* z1b = ws + Z1B_OFF;
  float* xt3 = ws + XT3_OFF;
  int* cnt = (int*)(ws + CNT_OFF);
  int* rowptr = (int*)(ws + ROWPTR_OFF);
  int* cur = (int*)(ws + CUR_OFF);
  int* bsum = (int*)(ws + BSUM_OFF);
  int* boff = (int*)(ws + BOFF_OFF);
  uint2* ep = (uint2*)(ws + EP_OFF);
  float* out = (float*)d_out;

  // CSR build (two-level parallel scan)
  k_zero<<<dim3(NB), dim3(256), 0, stream>>>(cnt);
  k_hist<<<dim3(3125), dim3(256), 0, stream>>>(row, cnt);
  k_blocksum<<<dim3(NB), dim3(256), 0, stream>>>(cnt, bsum);
  k_scanb<<<dim3(1), dim3(256), 0, stream>>>(bsum, boff);
  k_apply<<<dim3(NB), dim3(256), 0, stream>>>(cnt, boff, rowptr, cur);
  k_scatter<<<dim3(3125), dim3(256), 0, stream>>>(row, col, ew, cur, ep);

  // layer 1: split-K=2 MFMA GEMM -> z partials, then fast node chain (in-place)
  prep_wfrag<<<dim3(92), dim3(256), 0, stream>>>(W1, wfrag);
  gemm_half<<<dim3(782, 2), dim3(256), 0, stream>>>(x, wfrag, z1a);
  node1<<<dim3(12500), dim3(256), 0, stream>>>(z1a, z1b, b1, z1a);

  agg1_node2<<<dim3(12500), dim3(256), 0, stream>>>(rowptr, ep, z1a, W2, b2, xt3);
  agg2_final<<<dim3(1563), dim3(256), 0, stream>>>(rowptr, ep, xt3, out);
}